// Round 1
// baseline (5707.807 us; speedup 1.0000x reference)
//
#include <hip/hip_runtime.h>
#include <cstdint>
#include <cstddef>

#define EPSV 1e-5f

__device__ __forceinline__ int swz(int k, int m) { return m ^ ((k & 7) << 2); }

// ---------------- K1: reduce 1x1-conv GEMM + bias + BN + ReLU ----------------
// x[b,o,hw] = relu(bn(sum_c feat[b,c,hw]*W[o,c] + bias[o]))
// grid (4, 8, 64), block 256
__global__ __launch_bounds__(256) void k_reduce(
    const float* __restrict__ feat, const float* __restrict__ W,
    const float* __restrict__ bias, const float* __restrict__ gamma,
    const float* __restrict__ beta, const float* __restrict__ mean,
    const float* __restrict__ var, float* __restrict__ x)
{
  const int b = blockIdx.z;
  const int m0 = blockIdx.y * 64;
  const int n0 = blockIdx.x * 64;
  __shared__ float As[32][64];
  __shared__ float Bs[32][64];
  const int t = threadIdx.x;
  const int tx4 = (t & 15) * 4, ty4 = (t >> 4) * 4;
  const float* fb = feat + (size_t)b * 2048 * 196;
  float acc[4][4] = {};
  for (int k0 = 0; k0 < 2048; k0 += 32) {
    #pragma unroll
    for (int e = t; e < 2048; e += 256) {
      int m = e >> 5, k = e & 31;
      As[k][swz(k, m)] = W[(size_t)(m0 + m) * 2048 + (k0 + k)];
    }
    #pragma unroll
    for (int e = t; e < 2048; e += 256) {
      int k = e >> 6, n = e & 63;
      int hw = n0 + n;
      Bs[k][n] = (hw < 196) ? fb[(size_t)(k0 + k) * 196 + hw] : 0.f;
    }
    __syncthreads();
    #pragma unroll
    for (int k = 0; k < 32; ++k) {
      const float4 av = *(const float4*)&As[k][swz(k, ty4)];
      const float4 bv = *(const float4*)&Bs[k][tx4];
      const float a4[4] = {av.x, av.y, av.z, av.w};
      const float b4[4] = {bv.x, bv.y, bv.z, bv.w};
      #pragma unroll
      for (int i = 0; i < 4; ++i)
        #pragma unroll
        for (int j = 0; j < 4; ++j) acc[i][j] += a4[i] * b4[j];
    }
    __syncthreads();
  }
  #pragma unroll
  for (int i = 0; i < 4; ++i) {
    const int o = m0 + ty4 + i;
    const float inv = gamma[o] * rsqrtf(var[o] + EPSV);
    const float sh = beta[o] - mean[o] * inv;
    const float bi = bias[o];
    #pragma unroll
    for (int j = 0; j < 4; ++j) {
      const int hw = n0 + tx4 + j;
      if (hw < 196) {
        float v = (acc[i][j] + bi) * inv + sh;
        x[((size_t)b * 512 + o) * 196 + hw] = fmaxf(v, 0.f);
      }
    }
  }
}

// ---------------- K2a: s[b,i,j] = -sum_k x[b,i,k]*x[b,j,k] ----------------
// grid (8, 8, 64), block 256
__global__ __launch_bounds__(256) void k_xxt(
    const float* __restrict__ x, float* __restrict__ s)
{
  const int b = blockIdx.z;
  const int m0 = blockIdx.y * 64, n0 = blockIdx.x * 64;
  __shared__ float As[49][64];
  __shared__ float Bs[49][64];
  const int t = threadIdx.x;
  const int tx4 = (t & 15) * 4, ty4 = (t >> 4) * 4;
  const float* xb = x + (size_t)b * 512 * 196;
  float acc[4][4] = {};
  for (int k0 = 0; k0 < 196; k0 += 49) {
    for (int e = t; e < 49 * 64; e += 256) {
      int m = e / 49, k = e - m * 49;
      As[k][swz(k, m)] = xb[(size_t)(m0 + m) * 196 + (k0 + k)];
      Bs[k][swz(k, m)] = xb[(size_t)(n0 + m) * 196 + (k0 + k)];
    }
    __syncthreads();
    #pragma unroll
    for (int k = 0; k < 49; ++k) {
      const float4 av = *(const float4*)&As[k][swz(k, ty4)];
      const float4 bv = *(const float4*)&Bs[k][swz(k, tx4)];
      const float a4[4] = {av.x, av.y, av.z, av.w};
      const float b4[4] = {bv.x, bv.y, bv.z, bv.w};
      #pragma unroll
      for (int i = 0; i < 4; ++i)
        #pragma unroll
        for (int j = 0; j < 4; ++j) acc[i][j] += a4[i] * b4[j];
    }
    __syncthreads();
  }
  #pragma unroll
  for (int i = 0; i < 4; ++i)
    #pragma unroll
    for (int j = 0; j < 4; ++j)
      s[((size_t)b * 512 + (m0 + ty4 + i)) * 512 + (n0 + tx4 + j)] = -acc[i][j];
}

// ---------------- K2b: in-place row softmax over 512 cols ----------------
// grid (64*512), block 256
__global__ __launch_bounds__(256) void k_softmax(float* __restrict__ s)
{
  const int row = blockIdx.x;
  float* r = s + (size_t)row * 512;
  const int t = threadIdx.x;
  __shared__ float red[16];
  float v0 = r[t], v1 = r[t + 256];
  float m = fmaxf(v0, v1);
  #pragma unroll
  for (int off = 32; off; off >>= 1) m = fmaxf(m, __shfl_down(m, off));
  if ((t & 63) == 0) red[t >> 6] = m;
  __syncthreads();
  if (t == 0) red[8] = fmaxf(fmaxf(red[0], red[1]), fmaxf(red[2], red[3]));
  __syncthreads();
  const float mm = red[8];
  float e0 = __expf(v0 - mm), e1 = __expf(v1 - mm);
  float sum = e0 + e1;
  #pragma unroll
  for (int off = 32; off; off >>= 1) sum += __shfl_down(sum, off);
  if ((t & 63) == 0) red[t >> 6] = sum;
  __syncthreads();
  if (t == 0) red[9] = red[0] + red[1] + red[2] + red[3];
  __syncthreads();
  const float inv = 1.f / red[9];
  r[t] = e0 * inv;
  r[t + 256] = e1 * inv;
}

// ---------------- K3: y = att @ x  ----------------
// grid (4, 8, 64), block 256
__global__ __launch_bounds__(256) void k_attv(
    const float* __restrict__ att, const float* __restrict__ x,
    float* __restrict__ y)
{
  const int b = blockIdx.z;
  const int m0 = blockIdx.y * 64, n0 = blockIdx.x * 64;
  __shared__ float As[32][64];
  __shared__ float Bs[32][64];
  const int t = threadIdx.x;
  const int tx4 = (t & 15) * 4, ty4 = (t >> 4) * 4;
  const float* ab = att + (size_t)b * 512 * 512;
  const float* xb = x + (size_t)b * 512 * 196;
  float acc[4][4] = {};
  for (int k0 = 0; k0 < 512; k0 += 32) {
    #pragma unroll
    for (int e = t; e < 2048; e += 256) {
      int m = e >> 5, k = e & 31;
      As[k][swz(k, m)] = ab[(size_t)(m0 + m) * 512 + (k0 + k)];
    }
    #pragma unroll
    for (int e = t; e < 2048; e += 256) {
      int k = e >> 6, n = e & 63;
      int hw = n0 + n;
      Bs[k][n] = (hw < 196) ? xb[(size_t)(k0 + k) * 196 + hw] : 0.f;
    }
    __syncthreads();
    #pragma unroll
    for (int k = 0; k < 32; ++k) {
      const float4 av = *(const float4*)&As[k][swz(k, ty4)];
      const float4 bv = *(const float4*)&Bs[k][tx4];
      const float a4[4] = {av.x, av.y, av.z, av.w};
      const float b4[4] = {bv.x, bv.y, bv.z, bv.w};
      #pragma unroll
      for (int i = 0; i < 4; ++i)
        #pragma unroll
        for (int j = 0; j < 4; ++j) acc[i][j] += a4[i] * b4[j];
    }
    __syncthreads();
  }
  #pragma unroll
  for (int i = 0; i < 4; ++i) {
    const int o = m0 + ty4 + i;
    #pragma unroll
    for (int j = 0; j < 4; ++j) {
      const int hw = n0 + tx4 + j;
      if (hw < 196) y[((size_t)b * 512 + o) * 196 + hw] = acc[i][j];
    }
  }
}

// ---------------- K4: 3x3 conv (implicit GEMM) + bias + BN + ReLU ----------------
// W viewed as [512][4608]; B tile is on-the-fly im2col of y.
// grid (4, 8, 64), block 256
__global__ __launch_bounds__(256) void k_conv(
    const float* __restrict__ y, const float* __restrict__ W,
    const float* __restrict__ bias, const float* __restrict__ gamma,
    const float* __restrict__ beta, const float* __restrict__ mean,
    const float* __restrict__ var, float* __restrict__ zs)
{
  const int b = blockIdx.z;
  const int m0 = blockIdx.y * 64, n0 = blockIdx.x * 64;
  __shared__ float As[36][64];
  __shared__ float Bs[36][64];
  const int t = threadIdx.x;
  const int tx4 = (t & 15) * 4, ty4 = (t >> 4) * 4;
  const float* yb = y + (size_t)b * 512 * 196;
  float acc[4][4] = {};
  for (int k0 = 0; k0 < 4608; k0 += 36) {
    for (int e = t; e < 36 * 64; e += 256) {
      int m = e / 36, k = e - m * 36;
      As[k][swz(k, m)] = W[(size_t)(m0 + m) * 4608 + (k0 + k)];
    }
    for (int e = t; e < 36 * 64; e += 256) {
      int k = e >> 6, n = e & 63;
      int kk = k0 + k;
      int ic = kk / 9, r = kk - ic * 9;
      int kh = r / 3, kw = r - kh * 3;
      int hw = n0 + n;
      float v = 0.f;
      if (hw < 196) {
        int h = hw / 14, wc = hw - h * 14;
        int hy = h + kh - 1, wx = wc + kw - 1;
        if ((unsigned)hy < 14u && (unsigned)wx < 14u)
          v = yb[(size_t)ic * 196 + hy * 14 + wx];
      }
      Bs[k][n] = v;
    }
    __syncthreads();
    #pragma unroll
    for (int k = 0; k < 36; ++k) {
      const float4 av = *(const float4*)&As[k][swz(k, ty4)];
      const float4 bv = *(const float4*)&Bs[k][tx4];
      const float a4[4] = {av.x, av.y, av.z, av.w};
      const float b4[4] = {bv.x, bv.y, bv.z, bv.w};
      #pragma unroll
      for (int i = 0; i < 4; ++i)
        #pragma unroll
        for (int j = 0; j < 4; ++j) acc[i][j] += a4[i] * b4[j];
    }
    __syncthreads();
  }
  #pragma unroll
  for (int i = 0; i < 4; ++i) {
    const int o = m0 + ty4 + i;
    const float inv = gamma[o] * rsqrtf(var[o] + EPSV);
    const float sh = beta[o] - mean[o] * inv;
    const float bi = bias[o];
    #pragma unroll
    for (int j = 0; j < 4; ++j) {
      const int hw = n0 + tx4 + j;
      if (hw < 196) {
        float v = (acc[i][j] + bi) * inv + sh;
        zs[((size_t)b * 512 + o) * 196 + hw] = fmaxf(v, 0.f);
      }
    }
  }
}

// ---------------- K4b: global average pool ----------------
// grid (512, 64), block 64
__global__ __launch_bounds__(64) void k_pool(
    const float* __restrict__ zs, float* __restrict__ z)
{
  const int oc = blockIdx.x, b = blockIdx.y;
  const int t = threadIdx.x;
  const float* p = zs + ((size_t)b * 512 + oc) * 196;
  float sum = 0.f;
  for (int i = t; i < 196; i += 64) sum += p[i];
  #pragma unroll
  for (int off = 32; off; off >>= 1) sum += __shfl_down(sum, off);
  if (t == 0) z[(size_t)b * 512 + oc] = sum * (1.f / 196.f);
}

// ---------------- K5a: h = relu(z @ fc1_w^T + fc1_b) ----------------
// grid (64), block 256
__global__ __launch_bounds__(256) void k_fc1(
    const float* __restrict__ z, const float* __restrict__ w,
    const float* __restrict__ bi, float* __restrict__ h)
{
  const int b = blockIdx.x, t = threadIdx.x;
  __shared__ float zb[512];
  for (int i = t; i < 512; i += 256) zb[i] = z[(size_t)b * 512 + i];
  __syncthreads();
  if (t < 200) {
    float a = bi[t];
    const float* wr = w + (size_t)t * 512;
    for (int c = 0; c < 512; ++c) a += zb[c] * wr[c];
    h[(size_t)b * 200 + t] = fmaxf(a, 0.f);
  }
}

// ---------------- K5b: out = (h1+h2) @ fc2_w^T + 2*fc2_b ----------------
// grid (64), block 256
__global__ __launch_bounds__(256) void k_fc2(
    const float* __restrict__ h1, const float* __restrict__ h2,
    const float* __restrict__ w, const float* __restrict__ bi,
    float* __restrict__ out)
{
  const int b = blockIdx.x, t = threadIdx.x;
  __shared__ float hb[200];
  for (int i = t; i < 200; i += 256) hb[i] = h1[(size_t)b * 200 + i] + h2[(size_t)b * 200 + i];
  __syncthreads();
  if (t < 200) {
    float a = 2.f * bi[t];
    const float* wr = w + (size_t)t * 200;
    for (int j = 0; j < 200; ++j) a += hb[j] * wr[j];
    out[(size_t)b * 200 + t] = a;
  }
}

extern "C" void kernel_launch(void* const* d_in, const int* in_sizes, int n_in,
                              void* d_out, int out_size, void* d_ws, size_t ws_size,
                              hipStream_t stream) {
  const float* feat2     = (const float*)d_in[0];
  const float* feat3     = (const float*)d_in[1];
  const float* reduce_w  = (const float*)d_in[2];
  const float* reduce_b  = (const float*)d_in[3];
  const float* reduce_g  = (const float*)d_in[4];
  const float* reduce_be = (const float*)d_in[5];
  const float* reduce_m  = (const float*)d_in[6];
  const float* reduce_v  = (const float*)d_in[7];
  const float* conv3_w   = (const float*)d_in[8];
  const float* conv3_b   = (const float*)d_in[9];
  const float* conv3_g   = (const float*)d_in[10];
  const float* conv3_be  = (const float*)d_in[11];
  const float* conv3_m   = (const float*)d_in[12];
  const float* conv3_v   = (const float*)d_in[13];
  const float* fc1_w     = (const float*)d_in[14];
  const float* fc1_b     = (const float*)d_in[15];
  const float* fc2_w     = (const float*)d_in[16];
  const float* fc2_b     = (const float*)d_in[17];

  char* ws = (char*)d_ws;
  float* x   = (float*)(ws);                         // 25,690,112 B
  float* att = (float*)(ws + 25690112);              // 67,108,864 B
  float* y   = (float*)(ws + 25690112 + 67108864);   // 25,690,112 B
  float* zs  = att;                                  // reuse att region for conv output
  float* z   = (float*)(ws + 118489088);             // 131,072 B
  float* h1  = (float*)(ws + 118489088 + 131072);    // 51,200 B
  float* h2  = h1 + 64 * 200;                        // 51,200 B

  for (int br = 0; br < 2; ++br) {
    const float* feat = br ? feat3 : feat2;
    float* h = br ? h2 : h1;
    k_reduce<<<dim3(4, 8, 64), 256, 0, stream>>>(feat, reduce_w, reduce_b,
        reduce_g, reduce_be, reduce_m, reduce_v, x);
    k_xxt<<<dim3(8, 8, 64), 256, 0, stream>>>(x, att);
    k_softmax<<<dim3(64 * 512), 256, 0, stream>>>(att);
    k_attv<<<dim3(4, 8, 64), 256, 0, stream>>>(att, x, y);
    k_conv<<<dim3(4, 8, 64), 256, 0, stream>>>(y, conv3_w, conv3_b,
        conv3_g, conv3_be, conv3_m, conv3_v, zs);
    k_pool<<<dim3(512, 64), 64, 0, stream>>>(zs, z);
    k_fc1<<<dim3(64), 256, 0, stream>>>(z, fc1_w, fc1_b, h);
  }
  k_fc2<<<dim3(64), 256, 0, stream>>>(h1, h2, fc2_w, fc2_b, (float*)d_out);
}

// Round 5
// 1323.419 us; speedup vs baseline: 4.3129x; 4.3129x over previous
//
#include <hip/hip_runtime.h>
#include <cstdint>
#include <cstddef>

#define EPSV 1e-5f
#define HWP 224   // padded spatial (196 -> 224 = 14*16)

typedef __attribute__((ext_vector_type(8))) short short8;
typedef __attribute__((ext_vector_type(4))) short short4v;
typedef __attribute__((ext_vector_type(4))) float f32x4;

__device__ __forceinline__ unsigned short f2bf(float f) {
  unsigned u = __float_as_uint(f);
  u += 0x7FFFu + ((u >> 16) & 1u);
  return (unsigned short)(u >> 16);
}

// ---------------- cast Wr [512][2048] fp32 -> bf16 ----------------
__global__ __launch_bounds__(256) void k_cast_wr(
    const float* __restrict__ in, unsigned short* __restrict__ out) {
  int i = blockIdx.x * 256 + threadIdx.x;   // one float4 per thread
  if (i < 512 * 2048 / 4) {
    float4 v = ((const float4*)in)[i];
    short4v q = { (short)f2bf(v.x), (short)f2bf(v.y), (short)f2bf(v.z), (short)f2bf(v.w) };
    *(short4v*)&out[i * 4] = q;
  }
}

// -------- cast+permute conv3_w [o][ic][r] -> WcP[r][o][ic] bf16 --------
__global__ __launch_bounds__(256) void k_cast_wc(
    const float* __restrict__ in, unsigned short* __restrict__ out) {
  int idx = blockIdx.x * 256 + threadIdx.x;
  if (idx < 512 * 512 * 9) {
    float v = in[idx];
    int o = idx / 4608, rem = idx - o * 4608;
    int ic = rem / 9, r = rem - ic * 9;
    out[((size_t)r * 512 + o) * 512 + ic] = f2bf(v);
  }
}

// ------- cast+transpose feat[b][2048][196] fp32 -> featT[b][224][2048] bf16 -------
__global__ __launch_bounds__(256) void k_castT(
    const float* __restrict__ feat, unsigned short* __restrict__ featT) {
  __shared__ float tile[32][33];
  const int b = blockIdx.z, c0 = blockIdx.y * 32, hw0 = blockIdx.x * 32;
  const float* fb = feat + (size_t)b * 2048 * 196;
  const int t = threadIdx.x;
  int j = t & 31, i0 = t >> 5;          // j: hw-local, i: c-local
  #pragma unroll
  for (int i = i0; i < 32; i += 8) {
    int hw = hw0 + j;
    tile[i][j] = (hw < 196) ? fb[(size_t)(c0 + i) * 196 + hw] : 0.f;
  }
  __syncthreads();
  int jj = t >> 3, ii0 = (t & 7) * 4;
  unsigned short* ob = featT + ((size_t)b * HWP + hw0 + jj) * 2048 + c0 + ii0;
  short4v q = { (short)f2bf(tile[ii0][jj]), (short)f2bf(tile[ii0 + 1][jj]),
                (short)f2bf(tile[ii0 + 2][jj]), (short)f2bf(tile[ii0 + 3][jj]) };
  *(short4v*)ob = q;
}

// ---------------- K1: reduce GEMM (MFMA) + bias + BN + ReLU ----------------
// x[b][o][hw] (bf16, pad cols zeroed) and xT[b][hw][o] (bf16)
// grid (4, 64), block 256
__global__ __launch_bounds__(256) void k_reduce(
    const unsigned short* __restrict__ featT, const unsigned short* __restrict__ Wr,
    const float* __restrict__ bias, const float* __restrict__ gamma,
    const float* __restrict__ beta, const float* __restrict__ mean,
    const float* __restrict__ var,
    unsigned short* __restrict__ x, unsigned short* __restrict__ xT) {
  __shared__ short A_s[128][64];
  __shared__ short B_s[HWP][64];
  const int b = blockIdx.y, m0 = blockIdx.x * 128;
  const int t = threadIdx.x, lane = t & 63, wv = t >> 6;
  const int wm = wv >> 1, wn = wv & 1;
  const int lr = lane >> 4, lc = lane & 15;
  const unsigned short* fT = featT + (size_t)b * HWP * 2048;
  f32x4 acc[4][7] = {};
  for (int k0 = 0; k0 < 2048; k0 += 64) {
    #pragma unroll
    for (int id = t; id < 1024; id += 256) {
      int r = id >> 3, s = id & 7;
      short8 v = *(const short8*)(Wr + (size_t)(m0 + r) * 2048 + k0 + s * 8);
      *(short8*)&A_s[r][(s ^ (r & 7)) * 8] = v;
    }
    #pragma unroll
    for (int id = t; id < HWP * 8; id += 256) {
      int n = id >> 3, s = id & 7;
      short8 v = *(const short8*)(fT + (size_t)n * 2048 + k0 + s * 8);
      *(short8*)&B_s[n][(s ^ (n & 7)) * 8] = v;
    }
    __syncthreads();
    #pragma unroll
    for (int kk = 0; kk < 2; ++kk) {
      const int ks = kk * 4 + lr;
      short8 a[4], bf[7];
      #pragma unroll
      for (int mf = 0; mf < 4; ++mf) {
        int r = wm * 64 + mf * 16 + lc;
        a[mf] = *(const short8*)&A_s[r][(ks ^ (r & 7)) * 8];
      }
      #pragma unroll
      for (int nf = 0; nf < 7; ++nf) {
        int c = wn * 112 + nf * 16 + lc;
        bf[nf] = *(const short8*)&B_s[c][(ks ^ (c & 7)) * 8];
      }
      #pragma unroll
      for (int mf = 0; mf < 4; ++mf)
        #pragma unroll
        for (int nf = 0; nf < 7; ++nf)
          acc[mf][nf] = __builtin_amdgcn_mfma_f32_16x16x32_bf16(a[mf], bf[nf], acc[mf][nf], 0, 0, 0);
    }
    __syncthreads();
  }
  #pragma unroll
  for (int mf = 0; mf < 4; ++mf) {
    const int o0 = m0 + wm * 64 + mf * 16 + lr * 4;
    float inv[4], sh[4], bi[4];
    #pragma unroll
    for (int g = 0; g < 4; ++g) {
      int o = o0 + g;
      inv[g] = gamma[o] * rsqrtf(var[o] + EPSV);
      sh[g] = beta[o] - mean[o] * inv[g];
      bi[g] = bias[o];
    }
    #pragma unroll
    for (int nf = 0; nf < 7; ++nf) {
      const int col = wn * 112 + nf * 16 + lc;
      const bool valid = col < 196;
      unsigned short p[4];
      #pragma unroll
      for (int g = 0; g < 4; ++g) {
        float v = valid ? fmaxf((acc[mf][nf][g] + bi[g]) * inv[g] + sh[g], 0.f) : 0.f;
        p[g] = f2bf(v);
        x[((size_t)b * 512 + o0 + g) * HWP + col] = p[g];
      }
      short4v q = { (short)p[0], (short)p[1], (short)p[2], (short)p[3] };
      *(short4v*)&xT[((size_t)b * HWP + col) * 512 + o0] = q;
    }
  }
}

// ---------------- K2a: s[b][i][j] = -sum_hw x[i,hw]*x[j,hw] (MFMA) ----------------
// grid (4, 4, 64), block 256
__global__ __launch_bounds__(256) void k_xxt(
    const unsigned short* __restrict__ x, float* __restrict__ s) {
  __shared__ short A_s[128][64];
  __shared__ short B_s[128][64];
  const int b = blockIdx.z, m0 = blockIdx.y * 128, n0 = blockIdx.x * 128;
  const int t = threadIdx.x, lane = t & 63, wv = t >> 6;
  const int wm = wv >> 1, wn = wv & 1;
  const int lr = lane >> 4, lc = lane & 15;
  const unsigned short* xb = x + (size_t)b * 512 * HWP;
  f32x4 acc[4][4] = {};
  for (int k0 = 0; k0 < HWP; k0 += 64) {
    #pragma unroll
    for (int id = t; id < 1024; id += 256) {
      int r = id >> 3, ss = id & 7;
      int k = k0 + ss * 8;
      short8 z8 = {0, 0, 0, 0, 0, 0, 0, 0};
      short8 va = (k < HWP) ? *(const short8*)(xb + (size_t)(m0 + r) * HWP + k) : z8;
      short8 vb = (k < HWP) ? *(const short8*)(xb + (size_t)(n0 + r) * HWP + k) : z8;
      *(short8*)&A_s[r][(ss ^ (r & 7)) * 8] = va;
      *(short8*)&B_s[r][(ss ^ (r & 7)) * 8] = vb;
    }
    __syncthreads();
    #pragma unroll
    for (int kk = 0; kk < 2; ++kk) {
      const int ks = kk * 4 + lr;
      short8 a[4], bf[4];
      #pragma unroll
      for (int mf = 0; mf < 4; ++mf) {
        int r = wm * 64 + mf * 16 + lc;
        a[mf] = *(const short8*)&A_s[r][(ks ^ (r & 7)) * 8];
      }
      #pragma unroll
      for (int nf = 0; nf < 4; ++nf) {
        int c = wn * 64 + nf * 16 + lc;
        bf[nf] = *(const short8*)&B_s[c][(ks ^ (c & 7)) * 8];
      }
      #pragma unroll
      for (int mf = 0; mf < 4; ++mf)
        #pragma unroll
        for (int nf = 0; nf < 4; ++nf)
          acc[mf][nf] = __builtin_amdgcn_mfma_f32_16x16x32_bf16(a[mf], bf[nf], acc[mf][nf], 0, 0, 0);
    }
    __syncthreads();
  }
  #pragma unroll
  for (int mf = 0; mf < 4; ++mf)
    #pragma unroll
    for (int nf = 0; nf < 4; ++nf)
      #pragma unroll
      for (int g = 0; g < 4; ++g) {
        int i = m0 + wm * 64 + mf * 16 + lr * 4 + g;
        int j = n0 + wn * 64 + nf * 16 + lc;
        s[((size_t)b * 512 + i) * 512 + j] = -acc[mf][nf][g];
      }
}

// ---------------- K2b: in-place row softmax over 512 cols (fp32) ----------------
__global__ __launch_bounds__(256) void k_softmax(float* __restrict__ s) {
  const int row = blockIdx.x;
  float* r = s + (size_t)row * 512;
  const int t = threadIdx.x;
  __shared__ float red[16];
  float v0 = r[t], v1 = r[t + 256];
  float m = fmaxf(v0, v1);
  #pragma unroll
  for (int off = 32; off; off >>= 1) m = fmaxf(m, __shfl_down(m, off));
  if ((t & 63) == 0) red[t >> 6] = m;
  __syncthreads();
  if (t == 0) red[8] = fmaxf(fmaxf(red[0], red[1]), fmaxf(red[2], red[3]));
  __syncthreads();
  const float mm = red[8];
  float e0 = __expf(v0 - mm), e1 = __expf(v1 - mm);
  float sum = e0 + e1;
  #pragma unroll
  for (int off = 32; off; off >>= 1) sum += __shfl_down(sum, off);
  if ((t & 63) == 0) red[t >> 6] = sum;
  __syncthreads();
  if (t == 0) red[9] = red[0] + red[1] + red[2] + red[3];
  __syncthreads();
  const float inv = 1.f / red[9];
  r[t] = e0 * inv;
  r[t + 256] = e1 * inv;
}

// ---------------- K3: yT[b][hw][i] = sum_j att[i,j] * x[j,hw] (MFMA) ----------------
// grid (4, 64), block 256
__global__ __launch_bounds__(256) void k_attv(
    const float* __restrict__ att, const unsigned short* __restrict__ xT,
    unsigned short* __restrict__ yT) {
  __shared__ short A_s[128][64];
  __shared__ short B_s[HWP][64];
  const int b = blockIdx.y, m0 = blockIdx.x * 128;
  const int t = threadIdx.x, lane = t & 63, wv = t >> 6;
  const int wm = wv >> 1, wn = wv & 1;
  const int lr = lane >> 4, lc = lane & 15;
  const float* ab = att + (size_t)b * 512 * 512;
  const unsigned short* xTb = xT + (size_t)b * HWP * 512;
  f32x4 acc[4][7] = {};
  for (int k0 = 0; k0 < 512; k0 += 64) {
    #pragma unroll
    for (int id = t; id < 1024; id += 256) {
      int r = id >> 3, ss = id & 7;
      const float* sp = ab + (size_t)(m0 + r) * 512 + k0 + ss * 8;
      float4 f0 = *(const float4*)sp, f1 = *(const float4*)(sp + 4);
      short8 v = { (short)f2bf(f0.x), (short)f2bf(f0.y), (short)f2bf(f0.z), (short)f2bf(f0.w),
                   (short)f2bf(f1.x), (short)f2bf(f1.y), (short)f2bf(f1.z), (short)f2bf(f1.w) };
      *(short8*)&A_s[r][(ss ^ (r & 7)) * 8] = v;
    }
    #pragma unroll
    for (int id = t; id < HWP * 8; id += 256) {
      int n = id >> 3, ss = id & 7;
      short8 v = *(const short8*)(xTb + (size_t)n * 512 + k0 + ss * 8);
      *(short8*)&B_s[n][(ss ^ (n & 7)) * 8] = v;
    }
    __syncthreads();
    #pragma unroll
    for (int kk = 0; kk < 2; ++kk) {
      const int ks = kk * 4 + lr;
      short8 a[4], bf[7];
      #pragma unroll
      for (int mf = 0; mf < 4; ++mf) {
        int r = wm * 64 + mf * 16 + lc;
        a[mf] = *(const short8*)&A_s[r][(ks ^ (r & 7)) * 8];
      }
      #pragma unroll
      for (int nf = 0; nf < 7; ++nf) {
        int c = wn * 112 + nf * 16 + lc;
        bf[nf] = *(const short8*)&B_s[c][(ks ^ (c & 7)) * 8];
      }
      #pragma unroll
      for (int mf = 0; mf < 4; ++mf)
        #pragma unroll
        for (int nf = 0; nf < 7; ++nf)
          acc[mf][nf] = __builtin_amdgcn_mfma_f32_16x16x32_bf16(a[mf], bf[nf], acc[mf][nf], 0, 0, 0);
    }
    __syncthreads();
  }
  #pragma unroll
  for (int mf = 0; mf < 4; ++mf) {
    const int o0 = m0 + wm * 64 + mf * 16 + lr * 4;
    #pragma unroll
    for (int nf = 0; nf < 7; ++nf) {
      const int col = wn * 112 + nf * 16 + lc;
      short4v q = { (short)f2bf(acc[mf][nf][0]), (short)f2bf(acc[mf][nf][1]),
                    (short)f2bf(acc[mf][nf][2]), (short)f2bf(acc[mf][nf][3]) };
      *(short4v*)&yT[((size_t)b * HWP + col) * 512 + o0] = q;
    }
  }
}

// ------- K4: 3x3 conv as 9 shifted GEMMs (MFMA) + bias + BN + ReLU + avgpool -------
// grid (4, 64), block 256  ->  z[b][o] fp32
__global__ __launch_bounds__(256) void k_convpool(
    const unsigned short* __restrict__ yT, const unsigned short* __restrict__ WcP,
    const float* __restrict__ bias, const float* __restrict__ gamma,
    const float* __restrict__ beta, const float* __restrict__ mean,
    const float* __restrict__ var, float* __restrict__ z) {
  __shared__ short A_s[128][64];
  __shared__ short B_s[HWP][64];
  __shared__ float zp[2][128];
  const int b = blockIdx.y, m0 = blockIdx.x * 128;
  const int t = threadIdx.x, lane = t & 63, wv = t >> 6;
  const int wm = wv >> 1, wn = wv & 1;
  const int lr = lane >> 4, lc = lane & 15;
  const unsigned short* yTb = yT + (size_t)b * HWP * 512;
  // per-thread fixed B-staging geometry
  const int sslot = t & 7;
  int nn[7], hh[7], ww[7];
  bool nv[7];
  #pragma unroll
  for (int j = 0; j < 7; ++j) {
    int n = (t + j * 256) >> 3;
    nn[j] = n; nv[j] = n < 196;
    hh[j] = n / 14; ww[j] = n - (n / 14) * 14;
  }
  f32x4 acc[4][7] = {};
  #pragma unroll 1
  for (int r9 = 0; r9 < 9; ++r9) {
    const int dh = r9 / 3 - 1, dw = r9 - (r9 / 3) * 3 - 1;
    const unsigned short* Wp = WcP + ((size_t)r9 * 512 + m0) * 512;
    #pragma unroll 1
    for (int ict = 0; ict < 8; ++ict) {
      const int k0 = ict * 64;
      #pragma unroll
      for (int id = t; id < 1024; id += 256) {
        int r = id >> 3, ss = id & 7;
        short8 v = *(const short8*)(Wp + (size_t)r * 512 + k0 + ss * 8);
        *(short8*)&A_s[r][(ss ^ (r & 7)) * 8] = v;
      }
      #pragma unroll
      for (int j = 0; j < 7; ++j) {
        int n = nn[j];
        int hy = hh[j] + dh, wx = ww[j] + dw;
        short8 v = {0, 0, 0, 0, 0, 0, 0, 0};
        if (nv[j] && (unsigned)hy < 14u && (unsigned)wx < 14u)
          v = *(const short8*)(yTb + (size_t)(hy * 14 + wx) * 512 + k0 + sslot * 8);
        *(short8*)&B_s[n][(sslot ^ (n & 7)) * 8] = v;
      }
      __syncthreads();
      #pragma unroll
      for (int kk = 0; kk < 2; ++kk) {
        const int ks = kk * 4 + lr;
        short8 a[4], bf[7];
        #pragma unroll
        for (int mf = 0; mf < 4; ++mf) {
          int r = wm * 64 + mf * 16 + lc;
          a[mf] = *(const short8*)&A_s[r][(ks ^ (r & 7)) * 8];
        }
        #pragma unroll
        for (int nf = 0; nf < 7; ++nf) {
          int c = wn * 112 + nf * 16 + lc;
          bf[nf] = *(const short8*)&B_s[c][(ks ^ (c & 7)) * 8];
        }
        #pragma unroll
        for (int mf = 0; mf < 4; ++mf)
          #pragma unroll
          for (int nf = 0; nf < 7; ++nf)
            acc[mf][nf] = __builtin_amdgcn_mfma_f32_16x16x32_bf16(a[mf], bf[nf], acc[mf][nf], 0, 0, 0);
      }
      __syncthreads();
    }
  }
  // fused bias + BN + ReLU + mean-pool
  #pragma unroll
  for (int mf = 0; mf < 4; ++mf) {
    #pragma unroll
    for (int g = 0; g < 4; ++g) {
      const int lo = wm * 64 + mf * 16 + lr * 4 + g;
      const int o = m0 + lo;
      const float inv = gamma[o] * rsqrtf(var[o] + EPSV);
      const float sh = beta[o] - mean[o] * inv;
      const float bi = bias[o];
      float ss = 0.f;
      #pragma unroll
      for (int nf = 0; nf < 7; ++nf) {
        const int col = wn * 112 + nf * 16 + lc;
        float v = (acc[mf][nf][g] + bi) * inv + sh;
        if (col < 196) ss += fmaxf(v, 0.f);
      }
      ss += __shfl_xor(ss, 1);
      ss += __shfl_xor(ss, 2);
      ss += __shfl_xor(ss, 4);
      ss += __shfl_xor(ss, 8);
      if (lc == 0) zp[wn][lo] = ss;
    }
  }
  __syncthreads();
  if (t < 128) z[(size_t)b * 512 + m0 + t] = (zp[0][t] + zp[1][t]) * (1.f / 196.f);
}

// ---------------- K5a: h = relu(z @ fc1_w^T + fc1_b) ----------------
__global__ __launch_bounds__(256) void k_fc1(
    const float* __restrict__ z, const float* __restrict__ w,
    const float* __restrict__ bi, float* __restrict__ h) {
  const int b = blockIdx.x, t = threadIdx.x;
  __shared__ float zb[512];
  for (int i = t; i < 512; i += 256) zb[i] = z[(size_t)b * 512 + i];
  __syncthreads();
  if (t < 200) {
    float a = bi[t];
    const float* wr = w + (size_t)t * 512;
    for (int c = 0; c < 512; ++c) a += zb[c] * wr[c];
    h[(size_t)b * 200 + t] = fmaxf(a, 0.f);
  }
}

// ---------------- K5b: out = (h1+h2) @ fc2_w^T + 2*fc2_b ----------------
__global__ __launch_bounds__(256) void k_fc2(
    const float* __restrict__ h1, const float* __restrict__ h2,
    const float* __restrict__ w, const float* __restrict__ bi,
    float* __restrict__ out) {
  const int b = blockIdx.x, t = threadIdx.x;
  __shared__ float hb[200];
  for (int i = t; i < 200; i += 256) hb[i] = h1[(size_t)b * 200 + i] + h2[(size_t)b * 200 + i];
  __syncthreads();
  if (t < 200) {
    float a = 2.f * bi[t];
    const float* wr = w + (size_t)t * 200;
    for (int j = 0; j < 200; ++j) a += hb[j] * wr[j];
    out[(size_t)b * 200 + t] = a;
  }
}

extern "C" void kernel_launch(void* const* d_in, const int* in_sizes, int n_in,
                              void* d_out, int out_size, void* d_ws, size_t ws_size,
                              hipStream_t stream) {
  const float* feat2     = (const float*)d_in[0];
  const float* feat3     = (const float*)d_in[1];
  const float* reduce_w  = (const float*)d_in[2];
  const float* reduce_b  = (const float*)d_in[3];
  const float* reduce_g  = (const float*)d_in[4];
  const float* reduce_be = (const float*)d_in[5];
  const float* reduce_m  = (const float*)d_in[6];
  const float* reduce_v  = (const float*)d_in[7];
  const float* conv3_w   = (const float*)d_in[8];
  const float* conv3_b   = (const float*)d_in[9];
  const float* conv3_g   = (const float*)d_in[10];
  const float* conv3_be  = (const float*)d_in[11];
  const float* conv3_m   = (const float*)d_in[12];
  const float* conv3_v   = (const float*)d_in[13];
  const float* fc1_w     = (const float*)d_in[14];
  const float* fc1_b     = (const float*)d_in[15];
  const float* fc2_w     = (const float*)d_in[16];
  const float* fc2_b     = (const float*)d_in[17];

  char* ws = (char*)d_ws;
  // featT (58,720,256 B) and s (67,108,864 B) share region R (disjoint lifetimes)
  unsigned short* featT = (unsigned short*)(ws);
  float*          sbuf  = (float*)(ws);
  unsigned short* Wr    = (unsigned short*)(ws + 67108864);
  unsigned short* WcP   = (unsigned short*)(ws + 69206016);
  unsigned short* x     = (unsigned short*)(ws + 73924608);
  unsigned short* xT    = (unsigned short*)(ws + 88604672);
  unsigned short* yT    = (unsigned short*)(ws + 103284736);
  float*          z     = (float*)(ws + 117964800);
  float*          h1    = (float*)(ws + 118095872);
  float*          h2    = (float*)(ws + 118147072);

  k_cast_wr<<<dim3(1024), 256, 0, stream>>>(reduce_w, Wr);
  k_cast_wc<<<dim3(9216), 256, 0, stream>>>(conv3_w, WcP);

  for (int br = 0; br < 2; ++br) {
    const float* feat = br ? feat3 : feat2;
    float* h = br ? h2 : h1;
    k_castT<<<dim3(7, 64, 64), 256, 0, stream>>>(feat, featT);
    k_reduce<<<dim3(4, 64), 256, 0, stream>>>(featT, Wr, reduce_b,
        reduce_g, reduce_be, reduce_m, reduce_v, x, xT);
    k_xxt<<<dim3(4, 4, 64), 256, 0, stream>>>(x, sbuf);
    k_softmax<<<dim3(64 * 512), 256, 0, stream>>>(sbuf);
    k_attv<<<dim3(4, 64), 256, 0, stream>>>(sbuf, xT, yT);
    k_convpool<<<dim3(4, 64), 256, 0, stream>>>(yT, WcP, conv3_b,
        conv3_g, conv3_be, conv3_m, conv3_v, z);
    k_fc1<<<dim3(64), 256, 0, stream>>>(z, fc1_w, fc1_b, h);
  }
  k_fc2<<<dim3(64), 256, 0, stream>>>(h1, h2, fc2_w, fc2_b, (float*)d_out);
}

// Round 8
// 1023.176 us; speedup vs baseline: 5.5785x; 1.2934x over previous
//
#include <hip/hip_runtime.h>
#include <cstdint>
#include <cstddef>

#define EPSV 1e-5f
#define HWP 224   // padded spatial (196 -> 224 = 14*16)

typedef __attribute__((ext_vector_type(8))) short short8;
typedef __attribute__((ext_vector_type(4))) short short4v;
typedef __attribute__((ext_vector_type(4))) float f32x4;

__device__ __forceinline__ unsigned short f2bf(float f) {
  unsigned u = __float_as_uint(f);
  u += 0x7FFFu + ((u >> 16) & 1u);
  return (unsigned short)(u >> 16);
}

// ---------------- cast Wr [512][2048] fp32 -> bf16 ----------------
__global__ __launch_bounds__(256) void k_cast_wr(
    const float* __restrict__ in, unsigned short* __restrict__ out) {
  int i = blockIdx.x * 256 + threadIdx.x;   // one float4 per thread
  if (i < 512 * 2048 / 4) {
    float4 v = ((const float4*)in)[i];
    short4v q = { (short)f2bf(v.x), (short)f2bf(v.y), (short)f2bf(v.z), (short)f2bf(v.w) };
    *(short4v*)&out[i * 4] = q;
  }
}

// -------- cast+permute conv3_w [o][ic][r] -> WcP[r][o][ic] bf16 --------
__global__ __launch_bounds__(256) void k_cast_wc(
    const float* __restrict__ in, unsigned short* __restrict__ out) {
  int idx = blockIdx.x * 256 + threadIdx.x;
  if (idx < 512 * 512 * 9) {
    float v = in[idx];
    int o = idx / 4608, rem = idx - o * 4608;
    int ic = rem / 9, r = rem - ic * 9;
    out[((size_t)r * 512 + o) * 512 + ic] = f2bf(v);
  }
}

// ---------------- K1: reduce GEMM (MFMA) + bias + BN + ReLU ----------------
// feat fp32 [b][2048][196] read directly (in-staging cast + transpose).
// outputs x[b][o][hw] bf16 (pads zeroed) and xT[b][hw][o] bf16
// grid (4, 2, 64), block 256; BM=128 BN=112 BK=64; 4 m-waves
__global__ __launch_bounds__(256) void k_reduce(
    const float* __restrict__ feat, const unsigned short* __restrict__ Wr,
    const float* __restrict__ bias, const float* __restrict__ gamma,
    const float* __restrict__ beta, const float* __restrict__ mean,
    const float* __restrict__ var,
    unsigned short* __restrict__ x, unsigned short* __restrict__ xT) {
  __shared__ short A_s[128][64];
  __shared__ short B_s[112][64];
  const int b = blockIdx.z, m0 = blockIdx.x * 128, n0h = blockIdx.y * 112;
  const int t = threadIdx.x, lane = t & 63, wv = t >> 6;
  const int lr = lane >> 4, lc = lane & 15;
  const float* fb = feat + (size_t)b * 2048 * 196;
  f32x4 acc[2][7] = {};
  for (int k0 = 0; k0 < 2048; k0 += 64) {
    #pragma unroll
    for (int i = 0; i < 4; ++i) {
      int id = t + i * 256;
      int r = id >> 3, s = id & 7;
      short8 v = *(const short8*)(Wr + (size_t)(m0 + r) * 2048 + k0 + s * 8);
      *(short8*)&A_s[r][(s ^ (r & 7)) * 8] = v;
    }
    // B: 896 units, each = 4 n-cols x 2 k-rows, cast fp32->bf16, transpose
    #pragma unroll
    for (int i = 0; i < 4; ++i) {
      int u = t + i * 256;
      if (u < 896) {
        int ng = u % 28, kp = u / 28;
        int k = kp * 2, n = ng * 4, hw = n0h + n;
        float4 fa = {0.f, 0.f, 0.f, 0.f}, fc = {0.f, 0.f, 0.f, 0.f};
        if (hw < 196) {
          fa = *(const float4*)(fb + (size_t)(k0 + k) * 196 + hw);
          fc = *(const float4*)(fb + (size_t)(k0 + k + 1) * 196 + hw);
        }
        const float* pa = (const float*)&fa;
        const float* pc = (const float*)&fc;
        int s = kp >> 2, e = (kp & 3) * 2;
        #pragma unroll
        for (int j = 0; j < 4; ++j) {
          unsigned val = (unsigned)f2bf(pa[j]) | ((unsigned)f2bf(pc[j]) << 16);
          int n2 = n + j;
          *(unsigned*)&B_s[n2][(s ^ (n2 & 7)) * 8 + e] = val;
        }
      }
    }
    __syncthreads();
    #pragma unroll
    for (int kk = 0; kk < 2; ++kk) {
      const int ks = kk * 4 + lr;
      short8 a[2], bf[7];
      #pragma unroll
      for (int mf = 0; mf < 2; ++mf) {
        int r = wv * 32 + mf * 16 + lc;
        a[mf] = *(const short8*)&A_s[r][(ks ^ (r & 7)) * 8];
      }
      #pragma unroll
      for (int nf = 0; nf < 7; ++nf) {
        int c = nf * 16 + lc;
        bf[nf] = *(const short8*)&B_s[c][(ks ^ (c & 7)) * 8];
      }
      #pragma unroll
      for (int mf = 0; mf < 2; ++mf)
        #pragma unroll
        for (int nf = 0; nf < 7; ++nf)
          acc[mf][nf] = __builtin_amdgcn_mfma_f32_16x16x32_bf16(a[mf], bf[nf], acc[mf][nf], 0, 0, 0);
    }
    __syncthreads();
  }
  #pragma unroll
  for (int mf = 0; mf < 2; ++mf) {
    const int o0 = m0 + wv * 32 + mf * 16 + lr * 4;
    float inv[4], sh[4], bi[4];
    #pragma unroll
    for (int g = 0; g < 4; ++g) {
      int o = o0 + g;
      inv[g] = gamma[o] * rsqrtf(var[o] + EPSV);
      sh[g] = beta[o] - mean[o] * inv[g];
      bi[g] = bias[o];
    }
    #pragma unroll
    for (int nf = 0; nf < 7; ++nf) {
      const int col = n0h + nf * 16 + lc;
      const bool valid = col < 196;
      unsigned short p[4];
      #pragma unroll
      for (int g = 0; g < 4; ++g) {
        float v = valid ? fmaxf((acc[mf][nf][g] + bi[g]) * inv[g] + sh[g], 0.f) : 0.f;
        p[g] = f2bf(v);
        x[((size_t)b * 512 + o0 + g) * HWP + col] = p[g];
      }
      short4v q = { (short)p[0], (short)p[1], (short)p[2], (short)p[3] };
      *(short4v*)&xT[((size_t)b * HWP + col) * 512 + o0] = q;
    }
  }
}

// ---------------- K2a: s[b][i][j] = -sum_hw x[i,hw]*x[j,hw] (MFMA) ----------------
// grid (4, 4, 64), block 256
__global__ __launch_bounds__(256) void k_xxt(
    const unsigned short* __restrict__ x, float* __restrict__ s) {
  __shared__ short A_s[128][64];
  __shared__ short B_s[128][64];
  const int b = blockIdx.z, m0 = blockIdx.y * 128, n0 = blockIdx.x * 128;
  const int t = threadIdx.x, lane = t & 63, wv = t >> 6;
  const int wm = wv >> 1, wn = wv & 1;
  const int lr = lane >> 4, lc = lane & 15;
  const unsigned short* xb = x + (size_t)b * 512 * HWP;
  f32x4 acc[4][4] = {};
  for (int k0 = 0; k0 < HWP; k0 += 64) {
    #pragma unroll
    for (int id = t; id < 1024; id += 256) {
      int r = id >> 3, ss = id & 7;
      int k = k0 + ss * 8;
      // guard: last K-tile overhangs the 224-elem row (k up to 255) — zero-fill
      short8 z8 = {0, 0, 0, 0, 0, 0, 0, 0};
      short8 va = (k < HWP) ? *(const short8*)(xb + (size_t)(m0 + r) * HWP + k) : z8;
      short8 vb = (k < HWP) ? *(const short8*)(xb + (size_t)(n0 + r) * HWP + k) : z8;
      *(short8*)&A_s[r][(ss ^ (r & 7)) * 8] = va;
      *(short8*)&B_s[r][(ss ^ (r & 7)) * 8] = vb;
    }
    __syncthreads();
    #pragma unroll
    for (int kk = 0; kk < 2; ++kk) {
      const int ks = kk * 4 + lr;
      short8 a[4], bf[4];
      #pragma unroll
      for (int mf = 0; mf < 4; ++mf) {
        int r = wm * 64 + mf * 16 + lc;
        a[mf] = *(const short8*)&A_s[r][(ks ^ (r & 7)) * 8];
      }
      #pragma unroll
      for (int nf = 0; nf < 4; ++nf) {
        int c = wn * 64 + nf * 16 + lc;
        bf[nf] = *(const short8*)&B_s[c][(ks ^ (c & 7)) * 8];
      }
      #pragma unroll
      for (int mf = 0; mf < 4; ++mf)
        #pragma unroll
        for (int nf = 0; nf < 4; ++nf)
          acc[mf][nf] = __builtin_amdgcn_mfma_f32_16x16x32_bf16(a[mf], bf[nf], acc[mf][nf], 0, 0, 0);
    }
    __syncthreads();
  }
  #pragma unroll
  for (int mf = 0; mf < 4; ++mf)
    #pragma unroll
    for (int nf = 0; nf < 4; ++nf)
      #pragma unroll
      for (int g = 0; g < 4; ++g) {
        int i = m0 + wm * 64 + mf * 16 + lr * 4 + g;
        int j = n0 + wn * 64 + nf * 16 + lc;
        s[((size_t)b * 512 + i) * 512 + j] = -acc[mf][nf][g];
      }
}

// ---------------- K2b: in-place row softmax over 512 cols (fp32) ----------------
__global__ __launch_bounds__(256) void k_softmax(float* __restrict__ s) {
  const int row = blockIdx.x;
  float* r = s + (size_t)row * 512;
  const int t = threadIdx.x;
  __shared__ float red[16];
  float v0 = r[t], v1 = r[t + 256];
  float m = fmaxf(v0, v1);
  #pragma unroll
  for (int off = 32; off; off >>= 1) m = fmaxf(m, __shfl_down(m, off));
  if ((t & 63) == 0) red[t >> 6] = m;
  __syncthreads();
  if (t == 0) red[8] = fmaxf(fmaxf(red[0], red[1]), fmaxf(red[2], red[3]));
  __syncthreads();
  const float mm = red[8];
  float e0 = __expf(v0 - mm), e1 = __expf(v1 - mm);
  float sum = e0 + e1;
  #pragma unroll
  for (int off = 32; off; off >>= 1) sum += __shfl_down(sum, off);
  if ((t & 63) == 0) red[t >> 6] = sum;
  __syncthreads();
  if (t == 0) red[9] = red[0] + red[1] + red[2] + red[3];
  __syncthreads();
  const float inv = 1.f / red[9];
  r[t] = e0 * inv;
  r[t + 256] = e1 * inv;
}

// ---------------- K3: yT[b][hw][i] = sum_j att[i,j] * x[j,hw] (MFMA) ----------------
// grid (4, 2, 64), block 256; BM=128 BN=112 BK=64; 4 m-waves
__global__ __launch_bounds__(256) void k_attv(
    const float* __restrict__ att, const unsigned short* __restrict__ xT,
    unsigned short* __restrict__ yT) {
  __shared__ short A_s[128][64];
  __shared__ short B_s[112][64];
  const int b = blockIdx.z, m0 = blockIdx.x * 128, n0h = blockIdx.y * 112;
  const int t = threadIdx.x, lane = t & 63, wv = t >> 6;
  const int lr = lane >> 4, lc = lane & 15;
  const float* ab = att + (size_t)b * 512 * 512;
  const unsigned short* xTb = xT + (size_t)b * HWP * 512;
  f32x4 acc[2][7] = {};
  for (int k0 = 0; k0 < 512; k0 += 64) {
    #pragma unroll
    for (int i = 0; i < 4; ++i) {
      int id = t + i * 256;
      int r = id >> 3, ss = id & 7;
      const float* sp = ab + (size_t)(m0 + r) * 512 + k0 + ss * 8;
      float4 f0 = *(const float4*)sp, f1 = *(const float4*)(sp + 4);
      short8 v = { (short)f2bf(f0.x), (short)f2bf(f0.y), (short)f2bf(f0.z), (short)f2bf(f0.w),
                   (short)f2bf(f1.x), (short)f2bf(f1.y), (short)f2bf(f1.z), (short)f2bf(f1.w) };
      *(short8*)&A_s[r][(ss ^ (r & 7)) * 8] = v;
    }
    #pragma unroll
    for (int i = 0; i < 4; ++i) {
      int u = t + i * 256;
      if (u < 896) {
        int n = u >> 3, ss = u & 7;
        short8 v = *(const short8*)(xTb + (size_t)(n0h + n) * 512 + k0 + ss * 8);
        *(short8*)&B_s[n][(ss ^ (n & 7)) * 8] = v;
      }
    }
    __syncthreads();
    #pragma unroll
    for (int kk = 0; kk < 2; ++kk) {
      const int ks = kk * 4 + lr;
      short8 a[2], bf[7];
      #pragma unroll
      for (int mf = 0; mf < 2; ++mf) {
        int r = wv * 32 + mf * 16 + lc;
        a[mf] = *(const short8*)&A_s[r][(ks ^ (r & 7)) * 8];
      }
      #pragma unroll
      for (int nf = 0; nf < 7; ++nf) {
        int c = nf * 16 + lc;
        bf[nf] = *(const short8*)&B_s[c][(ks ^ (c & 7)) * 8];
      }
      #pragma unroll
      for (int mf = 0; mf < 2; ++mf)
        #pragma unroll
        for (int nf = 0; nf < 7; ++nf)
          acc[mf][nf] = __builtin_amdgcn_mfma_f32_16x16x32_bf16(a[mf], bf[nf], acc[mf][nf], 0, 0, 0);
    }
    __syncthreads();
  }
  #pragma unroll
  for (int mf = 0; mf < 2; ++mf) {
    const int o0 = m0 + wv * 32 + mf * 16 + lr * 4;
    #pragma unroll
    for (int nf = 0; nf < 7; ++nf) {
      const int col = n0h + nf * 16 + lc;
      short4v q = { (short)f2bf(acc[mf][nf][0]), (short)f2bf(acc[mf][nf][1]),
                    (short)f2bf(acc[mf][nf][2]), (short)f2bf(acc[mf][nf][3]) };
      *(short4v*)&yT[((size_t)b * HWP + col) * 512 + o0] = q;
    }
  }
}

// ------- K4: 3x3 conv as 9 shifted GEMMs (MFMA) + bias + BN + ReLU + partial avgpool -------
// grid (4, 2, 64), block 256 -> z2[half][b][o] raw sums (fp32)
__global__ __launch_bounds__(256) void k_convpool(
    const unsigned short* __restrict__ yT, const unsigned short* __restrict__ WcP,
    const float* __restrict__ bias, const float* __restrict__ gamma,
    const float* __restrict__ beta, const float* __restrict__ mean,
    const float* __restrict__ var, float* __restrict__ z2) {
  __shared__ short A_s[128][64];
  __shared__ short B_s[112][64];
  __shared__ float zp[128];
  const int b = blockIdx.z, m0 = blockIdx.x * 128, nhalf = blockIdx.y;
  const int n0h = nhalf * 112;
  const int t = threadIdx.x, lane = t & 63, wv = t >> 6;
  const int lr = lane >> 4, lc = lane & 15;
  const unsigned short* yTb = yT + (size_t)b * HWP * 512;
  // per-thread fixed B-staging geometry (4 units)
  int nn[4], hh[4], ww[4], sl[4];
  bool uv[4];
  #pragma unroll
  for (int j = 0; j < 4; ++j) {
    int u = t + j * 256;
    uv[j] = u < 896;
    int n = u >> 3;
    nn[j] = n; sl[j] = u & 7;
    int ng = n0h + n;
    hh[j] = ng / 14; ww[j] = ng - (ng / 14) * 14;
    if (ng >= 196) uv[j] = false;           // pad cols: leave zero
  }
  f32x4 acc[2][7] = {};
  #pragma unroll 1
  for (int r9 = 0; r9 < 9; ++r9) {
    const int dh = r9 / 3 - 1, dw = r9 - (r9 / 3) * 3 - 1;
    const unsigned short* Wp = WcP + ((size_t)r9 * 512 + m0) * 512;
    #pragma unroll 1
    for (int ict = 0; ict < 8; ++ict) {
      const int k0 = ict * 64;
      #pragma unroll
      for (int i = 0; i < 4; ++i) {
        int id = t + i * 256;
        int r = id >> 3, ss = id & 7;
        short8 v = *(const short8*)(Wp + (size_t)r * 512 + k0 + ss * 8);
        *(short8*)&A_s[r][(ss ^ (r & 7)) * 8] = v;
      }
      #pragma unroll
      for (int j = 0; j < 4; ++j) {
        if (t + j * 256 < 896) {
          int n = nn[j];
          int hy = hh[j] + dh, wx = ww[j] + dw;
          short8 v = {0, 0, 0, 0, 0, 0, 0, 0};
          if (uv[j] && (unsigned)hy < 14u && (unsigned)wx < 14u)
            v = *(const short8*)(yTb + (size_t)(hy * 14 + wx) * 512 + k0 + sl[j] * 8);
          *(short8*)&B_s[n][(sl[j] ^ (n & 7)) * 8] = v;
        }
      }
      __syncthreads();
      #pragma unroll
      for (int kk = 0; kk < 2; ++kk) {
        const int ks = kk * 4 + lr;
        short8 a[2], bf[7];
        #pragma unroll
        for (int mf = 0; mf < 2; ++mf) {
          int r = wv * 32 + mf * 16 + lc;
          a[mf] = *(const short8*)&A_s[r][(ks ^ (r & 7)) * 8];
        }
        #pragma unroll
        for (int nf = 0; nf < 7; ++nf) {
          int c = nf * 16 + lc;
          bf[nf] = *(const short8*)&B_s[c][(ks ^ (c & 7)) * 8];
        }
        #pragma unroll
        for (int mf = 0; mf < 2; ++mf)
          #pragma unroll
          for (int nf = 0; nf < 7; ++nf)
            acc[mf][nf] = __builtin_amdgcn_mfma_f32_16x16x32_bf16(a[mf], bf[nf], acc[mf][nf], 0, 0, 0);
      }
      __syncthreads();
    }
  }
  // fused bias + BN + ReLU + partial pool over this n-half
  #pragma unroll
  for (int mf = 0; mf < 2; ++mf) {
    #pragma unroll
    for (int g = 0; g < 4; ++g) {
      const int lo = wv * 32 + mf * 16 + lr * 4 + g;
      const int o = m0 + lo;
      const float inv = gamma[o] * rsqrtf(var[o] + EPSV);
      const float sh = beta[o] - mean[o] * inv;
      const float bi = bias[o];
      float ss = 0.f;
      #pragma unroll
      for (int nf = 0; nf < 7; ++nf) {
        const int col = n0h + nf * 16 + lc;
        float v = (acc[mf][nf][g] + bi) * inv + sh;
        if (col < 196) ss += fmaxf(v, 0.f);
      }
      ss += __shfl_xor(ss, 1);
      ss += __shfl_xor(ss, 2);
      ss += __shfl_xor(ss, 4);
      ss += __shfl_xor(ss, 8);
      if (lc == 0) zp[lo] = ss;
    }
  }
  __syncthreads();
  if (t < 128) z2[((size_t)nhalf * 64 + b) * 512 + m0 + t] = zp[t];
}

// ---------------- K5a: h = relu(((z2_0+z2_1)/196) @ fc1_w^T + fc1_b) ----------------
__global__ __launch_bounds__(256) void k_fc1(
    const float* __restrict__ z2, const float* __restrict__ w,
    const float* __restrict__ bi, float* __restrict__ h) {
  const int b = blockIdx.x, t = threadIdx.x;
  __shared__ float zb[512];
  for (int i = t; i < 512; i += 256)
    zb[i] = (z2[(size_t)b * 512 + i] + z2[(size_t)(64 + b) * 512 + i]) * (1.f / 196.f);
  __syncthreads();
  if (t < 200) {
    float a = bi[t];
    const float* wr = w + (size_t)t * 512;
    for (int c = 0; c < 512; ++c) a += zb[c] * wr[c];
    h[(size_t)b * 200 + t] = fmaxf(a, 0.f);
  }
}

// ---------------- K5b: out = (h1+h2) @ fc2_w^T + 2*fc2_b ----------------
__global__ __launch_bounds__(256) void k_fc2(
    const float* __restrict__ h1, const float* __restrict__ h2,
    const float* __restrict__ w, const float* __restrict__ bi,
    float* __restrict__ out) {
  const int b = blockIdx.x, t = threadIdx.x;
  __shared__ float hb[200];
  for (int i = t; i < 200; i += 256) hb[i] = h1[(size_t)b * 200 + i] + h2[(size_t)b * 200 + i];
  __syncthreads();
  if (t < 200) {
    float a = 2.f * bi[t];
    const float* wr = w + (size_t)t * 200;
    for (int j = 0; j < 200; ++j) a += hb[j] * wr[j];
    out[(size_t)b * 200 + t] = a;
  }
}

extern "C" void kernel_launch(void* const* d_in, const int* in_sizes, int n_in,
                              void* d_out, int out_size, void* d_ws, size_t ws_size,
                              hipStream_t stream) {
  const float* feat2     = (const float*)d_in[0];
  const float* feat3     = (const float*)d_in[1];
  const float* reduce_w  = (const float*)d_in[2];
  const float* reduce_b  = (const float*)d_in[3];
  const float* reduce_g  = (const float*)d_in[4];
  const float* reduce_be = (const float*)d_in[5];
  const float* reduce_m  = (const float*)d_in[6];
  const float* reduce_v  = (const float*)d_in[7];
  const float* conv3_w   = (const float*)d_in[8];
  const float* conv3_b   = (const float*)d_in[9];
  const float* conv3_g   = (const float*)d_in[10];
  const float* conv3_be  = (const float*)d_in[11];
  const float* conv3_m   = (const float*)d_in[12];
  const float* conv3_v   = (const float*)d_in[13];
  const float* fc1_w     = (const float*)d_in[14];
  const float* fc1_b     = (const float*)d_in[15];
  const float* fc2_w     = (const float*)d_in[16];
  const float* fc2_b     = (const float*)d_in[17];

  char* ws = (char*)d_ws;
  float*          sbuf = (float*)(ws);                    // 67,108,864 B (S logits)
  unsigned short* Wr   = (unsigned short*)(ws + 67108864); // 2,097,152 B
  unsigned short* WcP  = (unsigned short*)(ws + 69206016); // 4,718,592 B
  unsigned short* x    = (unsigned short*)(ws + 73924608); // 14,680,064 B
  unsigned short* xT   = (unsigned short*)(ws + 88604672); // 14,680,064 B
  unsigned short* yT   = (unsigned short*)(ws + 103284736);// 14,680,064 B
  float*          z2   = (float*)(ws + 117964800);         // 262,144 B (2 halves)
  float*          h1   = (float*)(ws + 118226944);         // 51,200 B
  float*          h2   = h1 + 64 * 200;                    // 51,200 B

  k_cast_wr<<<dim3(1024), 256, 0, stream>>>(reduce_w, Wr);
  k_cast_wc<<<dim3(9216), 256, 0, stream>>>(conv3_w, WcP);

  for (int br = 0; br < 2; ++br) {
    const float* feat = br ? feat3 : feat2;
    float* h = br ? h2 : h1;
    k_reduce<<<dim3(4, 2, 64), 256, 0, stream>>>(feat, Wr, reduce_b,
        reduce_g, reduce_be, reduce_m, reduce_v, x, xT);
    k_xxt<<<dim3(4, 4, 64), 256, 0, stream>>>(x, sbuf);
    k_softmax<<<dim3(64 * 512), 256, 0, stream>>>(sbuf);
    k_attv<<<dim3(4, 2, 64), 256, 0, stream>>>(sbuf, xT, yT);
    k_convpool<<<dim3(4, 2, 64), 256, 0, stream>>>(yT, WcP, conv3_b,
        conv3_g, conv3_be, conv3_m, conv3_v, z2);
    k_fc1<<<dim3(64), 256, 0, stream>>>(z2, fc1_w, fc1_b, h);
  }
  k_fc2<<<dim3(64), 256, 0, stream>>>(h1, h2, fc2_w, fc2_b, (float*)d_out);
}